// Round 1
// baseline (161.258 us; speedup 1.0000x reference)
//
#include <hip/hip_runtime.h>

#define HH 512
#define WW 512
#define NBATCH 16
#define NBINS 512   // 511 real shells + 1 overflow (never accumulated)

#define PI_F 3.14159265358979323846f

// Swizzle for the per-wave FFT exchange region (512 float2): keeps all three
// access phases at the conflict-free b64 baseline (verified R3, absmax 0).
#define SW(r) ((r) ^ (((r) >> 4) & 0xF))
// Swizzle for the 512x8 transpose tile: A = 8c + (hh ^ ((c>>1)&7)).
#define TSW(c, hh) (((c) << 3) + ((hh) ^ (((c) >> 1) & 7)))

__device__ __forceinline__ float2 cadd(float2 a, float2 b){ return make_float2(a.x+b.x, a.y+b.y); }
__device__ __forceinline__ float2 csub(float2 a, float2 b){ return make_float2(a.x-b.x, a.y-b.y); }
__device__ __forceinline__ float2 cmul(float2 a, float2 b){
    return make_float2(a.x*b.x - a.y*b.y, a.x*b.y + a.y*b.x);
}

// 8-point DFT, y_r = sum_u a_u * w8^{ru} (forward, w8 = exp(-i pi/4)).
__device__ __forceinline__ void dft8(const float2* a, float2* y) {
    const float s2 = 0.70710678118654752440f;
    float2 t02a = cadd(a[0], a[4]), t02s = csub(a[0], a[4]);
    float2 t13a = cadd(a[2], a[6]), t13s = csub(a[2], a[6]);
    float2 E0 = cadd(t02a, t13a);
    float2 E2 = csub(t02a, t13a);
    float2 E1 = make_float2(t02s.x + t13s.y, t02s.y - t13s.x);
    float2 E3 = make_float2(t02s.x - t13s.y, t02s.y + t13s.x);
    float2 u02a = cadd(a[1], a[5]), u02s = csub(a[1], a[5]);
    float2 u13a = cadd(a[3], a[7]), u13s = csub(a[3], a[7]);
    float2 O0 = cadd(u02a, u13a);
    float2 O2 = csub(u02a, u13a);
    float2 O1 = make_float2(u02s.x + u13s.y, u02s.y - u13s.x);
    float2 O3 = make_float2(u02s.x - u13s.y, u02s.y + u13s.x);
    float2 wO1 = make_float2(s2 * (O1.x + O1.y), s2 * (O1.y - O1.x));
    float2 wO2 = make_float2(O2.y, -O2.x);
    float2 wO3 = make_float2(s2 * (O3.y - O3.x), -s2 * (O3.x + O3.y));
    y[0] = cadd(E0, O0);  y[4] = csub(E0, O0);
    y[1] = cadd(E1, wO1); y[5] = csub(E1, wO1);
    y[2] = cadd(E2, wO2); y[6] = csub(E2, wO2);
    y[3] = cadd(E3, wO3); y[7] = csub(E3, wO3);
}

__device__ __forceinline__ void twiddle8(float base, float2* w) {
    float s1, c1, s4, c4;
    __sincosf(base, &s1, &c1);
    __sincosf(4.0f * base, &s4, &c4);
    w[0] = make_float2(1.0f, 0.0f);
    w[1] = make_float2(c1, s1);
    w[2] = cmul(w[1], w[1]);
    w[3] = cmul(w[2], w[1]);
    w[4] = make_float2(c4, s4);
    w[5] = cmul(w[4], w[1]);
    w[6] = cmul(w[4], w[2]);
    w[7] = cmul(w[4], w[3]);
}

// Radix-8 Stockham, N=512 (verified R3): 2 LDS round trips, wave-local.
__device__ __forceinline__ void fft512_stage0_store(float2* rb, int lane, const float2* a) {
    float2 y[8]; dft8(a, y);
    float2 w[8]; twiddle8(-PI_F * (float)lane * (1.0f / 256.0f), w);
#pragma unroll
    for (int r = 0; r < 8; ++r) rb[SW(8 * lane + r)] = cmul(y[r], w[r]);
}

__device__ __forceinline__ void fft512_stage1(float2* rb, int lane) {
    float2 a[8];
#pragma unroll
    for (int u = 0; u < 8; ++u) a[u] = rb[SW(lane + 64 * u)];
    float2 y[8]; dft8(a, y);
    float2 w[8]; twiddle8(-PI_F * (float)(lane >> 3) * (1.0f / 32.0f), w);
    const int qb = (lane & 7) + ((lane >> 3) << 6);
#pragma unroll
    for (int r = 0; r < 8; ++r) rb[SW(qb + 8 * r)] = cmul(y[r], w[r]);
}

__device__ __forceinline__ void fft512_stage2(const float2* rb, int lane, float2* y) {
    float2 a[8];
#pragma unroll
    for (int u = 0; u < 8; ++u) a[u] = rb[SW(lane + 64 * u)];
    dft8(a, y);   // twiddle-free; y[r] = X[lane + 64r] (natural order)
}

// ---------------------------------------------------------------------------
// Row pass: unchanged from the 158 us version (2.8 TB/s effective).
// ---------------------------------------------------------------------------
__global__ __launch_bounds__(512, 4)
void row_fft_kernel(const float2* __restrict__ z, const float2* __restrict__ t,
                    float2* __restrict__ fieldsT, int b0) {
    __shared__ float2 buf[8 * 512];   // 32 KiB: FFT regions, then transpose tile
    const int tid  = threadIdx.x;
    const int lane = tid & 63;
    const int g    = tid >> 6;
    const int bid  = blockIdx.x;
    const int hg   = bid & 63;
    const int lb   = bid >> 6;
    const int b    = b0 + lb;
    const int h    = (hg << 3) | g;
    const size_t rowOff = ((size_t)(b * HH + h)) * WW;

    const float2* tr = t + rowOff;
    const float2* zr = z + rowOff;
    float2 tv[8], zv[8];
#pragma unroll
    for (int u = 0; u < 8; ++u) tv[u] = tr[lane + 64 * u];
#pragma unroll
    for (int u = 0; u < 8; ++u) zv[u] = zr[lane + 64 * u];

    float2* rb = buf + (g << 9);
#pragma unroll
    for (int f = 0; f < 2; ++f) {
        float2 a[8];
        if (f == 0) {
#pragma unroll
            for (int u = 0; u < 8; ++u) a[u] = tv[u];
        } else {
#pragma unroll
            for (int u = 0; u < 8; ++u) a[u] = make_float2(zv[u].x - tv[u].x,
                                                           zv[u].y - tv[u].y);
        }
        fft512_stage0_store(rb, lane, a);
        __builtin_amdgcn_wave_barrier();
        fft512_stage1(rb, lane);
        __builtin_amdgcn_wave_barrier();
        float2 y[8];
        fft512_stage2(rb, lane, y);

        __syncthreads();   // all waves done reading their FFT regions
#pragma unroll
        for (int r = 0; r < 8; ++r) {
            int c = lane + (r << 6);
            buf[TSW(c, g)] = y[r];
        }
        __syncthreads();
        float2* outF = fieldsT + ((size_t)(lb * 2 + f) << 18);  // * 512*512
#pragma unroll
        for (int k = 0; k < 8; ++k) {
            int e  = tid + (k << 9);
            int c  = e >> 3;
            int hh = e & 7;
            outF[((size_t)c << 9) + (hg << 3) + hh] = buf[TSW(c, hh)];
        }
        __syncthreads();   // tile region free before next field's stage 0
    }
}

// ---------------------------------------------------------------------------
// Column pass: wave g owns column cg*8+g. Contiguous load -> wave-local FFT
// -> fused |X|^2 shell binning into a WAVE-PRIVATE histogram that reuses the
// wave's own (now free) FFT exchange region -- no cross-wave atomic
// contention, no block-shared hist LDS, only ONE __syncthreads. Bin index is
// exact integer math (no f64 sqrt): shell j satisfied iff
// j^2 * 65536 <= 261121 * m, m = dk^2 + dc^2 (all exact integers).
// Block output is a non-atomic coalesced 2 KiB store into a unique partials
// slot; a tiny reduction kernel sums the 64 column-group partials.
// grid = CB*2*64.
// ---------------------------------------------------------------------------
__global__ __launch_bounds__(512, 4)
void col_fft_bin_kernel(const float2* __restrict__ fieldsT,
                        float* __restrict__ partials, int b0) {
    __shared__ float2 buf[8 * 512];   // 32 KiB FFT exchange regions (reused as hists)
    const int tid  = threadIdx.x;
    const int lane = tid & 63;
    const int g    = tid >> 6;
    const int bid  = blockIdx.x;
    const int cg   = bid & 63;
    const int fl   = bid >> 6;
    const int f    = fl & 1;
    const int b    = b0 + (fl >> 1);
    const int c    = (cg << 3) | g;

    const float2* colT = fieldsT + (((size_t)fl << 9) + c) * 512;
    float2 a[8];
#pragma unroll
    for (int u = 0; u < 8; ++u) a[u] = colT[lane + (u << 6)];

    float2* rb = buf + (g << 9);
    fft512_stage0_store(rb, lane, a);
    __builtin_amdgcn_wave_barrier();
    fft512_stage1(rb, lane);
    __builtin_amdgcn_wave_barrier();
    float2 y[8];
    fft512_stage2(rb, lane, y);
    __builtin_amdgcn_wave_barrier();
    __asm__ volatile("" ::: "memory");   // stage2 reads complete before hist zeroing

    // Zero the wave's private 512-float hist (first 256 float2 of its region).
    // float2 stores: same type as the stage2 reads -> no TBAA reordering hazard.
#pragma unroll
    for (int j = 0; j < 4; ++j) rb[lane + (j << 6)] = make_float2(0.0f, 0.0f);
    __builtin_amdgcn_wave_barrier();
    __asm__ volatile("" ::: "memory");

    float* histw = (float*)rb;           // 512 wave-private bins
    const int dc = c - 256;
    const unsigned fc2i = (unsigned)(dc * dc);
#pragma unroll
    for (int r = 0; r < 8; ++r) {
        int k  = lane + (r << 6);
        int dk = k - 256;
        unsigned m = (unsigned)(dk * dk) + fc2i;   // 65536 * ellipse, exact
        if (m < 65536u) {                          // overflow shell dropped
            // bin = #{ j in [1,511] : (j/511)^2 <= m/65536 }, computed exactly:
            int bin = (int)(sqrtf((float)m) * (511.0f / 256.0f));
            unsigned long long rhs = 261121ull * (unsigned long long)m;  // 511^2 * m
            unsigned bp1 = (unsigned)(bin + 1);
            if (((unsigned long long)(bp1 * bp1) << 16) <= rhs) ++bin;
            else if (((unsigned long long)((unsigned)bin * (unsigned)bin) << 16) > rhs) --bin;
            atomicAdd(&histw[bin], y[r].x * y[r].x + y[r].y * y[r].y);
        }
    }
    __syncthreads();                     // all wave-private hists final

    // Cross-wave sum (fixed order) + coalesced non-atomic flush.
    float s = 0.0f;
    const float* bufF = (const float*)buf;
#pragma unroll
    for (int gg = 0; gg < 8; ++gg) s += bufF[(gg << 10) + tid];
    partials[(((size_t)cg << 5) + (size_t)(f * NBATCH + b)) * NBINS + tid] = s;
}

// ---------------------------------------------------------------------------
// Sum the 64 column-group partials: bins[fl][bin] = sum_cg partials[cg][fl][bin].
// grid = 128 blocks: block = (fl, quarter-of-bins); thread = (cg-chunk, bin).
// ---------------------------------------------------------------------------
__global__ __launch_bounds__(512)
void reduce_bins_kernel(const float* __restrict__ partials, float* __restrict__ bins) {
    __shared__ float red[512];
    const int tid = threadIdx.x;
    const int fl  = blockIdx.x >> 2;          // 0..31  (f*16+b)
    const int q   = blockIdx.x & 3;           // quarter of the 512 bins
    const int bin = (q << 7) + (tid & 127);
    const int ch  = tid >> 7;                 // 0..3 -> 16 cg each
    float s = 0.0f;
#pragma unroll
    for (int j = 0; j < 16; ++j) {
        int cg = (ch << 4) + j;
        s += partials[((size_t)(cg << 5) + fl) * NBINS + bin];
    }
    red[tid] = s;
    __syncthreads();
    if (tid < 128) {
        bins[(size_t)fl * NBINS + bin] =
            red[tid] + red[tid + 128] + red[tid + 256] + red[tid + 384];
    }
}

// ---------------------------------------------------------------------------
// Loss: single block reads the 64 KiB bins array.
// loss = mean_b sum_{k<511} es[b][k] / max(ns[b][k], 1e-8)
// ---------------------------------------------------------------------------
__global__ __launch_bounds__(512)
void loss_kernel(const float* __restrict__ bins, float* __restrict__ outp) {
    __shared__ float red[512];
    const int tid = threadIdx.x;
    float acc = 0.0f;
    if (tid < 511) {
#pragma unroll 4
        for (int b = 0; b < NBATCH; ++b) {
            float ns = bins[((size_t)b) * NBINS + tid];
            float es = bins[((size_t)(NBATCH + b)) * NBINS + tid];
            acc += es / fmaxf(ns, 1e-8f);
        }
    }
    red[tid] = acc;
    __syncthreads();
    for (int s = 256; s > 0; s >>= 1) {
        if (tid < s) red[tid] += red[tid + s];
        __syncthreads();
    }
    if (tid == 0) outp[0] = red[0] * (1.0f / NBATCH);
}

// ---------------------------------------------------------------------------
extern "C" void kernel_launch(void* const* d_in, const int* in_sizes, int n_in,
                              void* d_out, int out_size, void* d_ws, size_t ws_size,
                              hipStream_t stream) {
    const float2* z = (const float2*)d_in[0];
    const float2* t = (const float2*)d_in[1];
    float* outp = (float*)d_out;

    const size_t partialsBytes = 64ull * 2 * NBATCH * NBINS * sizeof(float);  // 4 MiB
    const size_t binsBytes     = (size_t)2 * NBATCH * NBINS * sizeof(float);  // 64 KiB
    const size_t fixedBytes    = partialsBytes + binsBytes;
    const size_t fpb = (size_t)2 * HH * WW * sizeof(float2);                  // 4 MiB/batch

    int CB = 16;
    while (CB > 1 && fixedBytes + (size_t)CB * fpb > ws_size) CB >>= 1;

    float*  partials = (float*)d_ws;
    float*  bins     = (float*)((char*)d_ws + partialsBytes);
    float2* fieldsT  = (float2*)((char*)d_ws + fixedBytes);

    // No memset needed: every partials slot and every bins slot is written
    // unconditionally (all cg x all (f,b) covered across the CB passes).
    for (int b0 = 0; b0 < NBATCH; b0 += CB) {
        row_fft_kernel<<<CB * 64, 512, 0, stream>>>(z, t, fieldsT, b0);
        col_fft_bin_kernel<<<CB * 2 * 64, 512, 0, stream>>>(fieldsT, partials, b0);
    }
    reduce_bins_kernel<<<128, 512, 0, stream>>>(partials, bins);
    loss_kernel<<<1, 512, 0, stream>>>(bins, outp);
}

// Round 2
// 157.564 us; speedup vs baseline: 1.0234x; 1.0234x over previous
//
#include <hip/hip_runtime.h>

#define HH 512
#define WW 512
#define NBATCH 16
#define NBINS 512   // 511 real shells + 1 overflow (never read downstream)

#define PI_F 3.14159265358979323846f

// Swizzle for the per-wave FFT exchange region (512 float2): keeps all three
// access phases at the conflict-free b64 baseline (verified R3, absmax 0).
#define SW(r) ((r) ^ (((r) >> 4) & 0xF))
// Swizzle for the 512x8 transpose tile: A = 8c + (hh ^ ((c>>1)&7)).
#define TSW(c, hh) (((c) << 3) + ((hh) ^ (((c) >> 1) & 7)))

// DPP helpers (VALU-only cross-lane within 16-lane rows; no LDS pipe).
// row_shr:n -> lane i receives src[i-n] (the AMD prefix-scan idiom).
// row_shl:n -> lane i receives src[i+n].
#define DPP_SHR(x, n) __builtin_amdgcn_update_dpp(0, (x), 0x110 + (n), 0xF, 0xF, true)
#define DPP_SHL1(x)   __builtin_amdgcn_update_dpp(0, (x), 0x101,       0xF, 0xF, true)

__device__ __forceinline__ float2 cadd(float2 a, float2 b){ return make_float2(a.x+b.x, a.y+b.y); }
__device__ __forceinline__ float2 csub(float2 a, float2 b){ return make_float2(a.x-b.x, a.y-b.y); }
__device__ __forceinline__ float2 cmul(float2 a, float2 b){
    return make_float2(a.x*b.x - a.y*b.y, a.x*b.y + a.y*b.x);
}

// 8-point DFT, y_r = sum_u a_u * w8^{ru} (forward, w8 = exp(-i pi/4)).
__device__ __forceinline__ void dft8(const float2* a, float2* y) {
    const float s2 = 0.70710678118654752440f;
    float2 t02a = cadd(a[0], a[4]), t02s = csub(a[0], a[4]);
    float2 t13a = cadd(a[2], a[6]), t13s = csub(a[2], a[6]);
    float2 E0 = cadd(t02a, t13a);
    float2 E2 = csub(t02a, t13a);
    float2 E1 = make_float2(t02s.x + t13s.y, t02s.y - t13s.x);
    float2 E3 = make_float2(t02s.x - t13s.y, t02s.y + t13s.x);
    float2 u02a = cadd(a[1], a[5]), u02s = csub(a[1], a[5]);
    float2 u13a = cadd(a[3], a[7]), u13s = csub(a[3], a[7]);
    float2 O0 = cadd(u02a, u13a);
    float2 O2 = csub(u02a, u13a);
    float2 O1 = make_float2(u02s.x + u13s.y, u02s.y - u13s.x);
    float2 O3 = make_float2(u02s.x - u13s.y, u02s.y + u13s.x);
    float2 wO1 = make_float2(s2 * (O1.x + O1.y), s2 * (O1.y - O1.x));
    float2 wO2 = make_float2(O2.y, -O2.x);
    float2 wO3 = make_float2(s2 * (O3.y - O3.x), -s2 * (O3.x + O3.y));
    y[0] = cadd(E0, O0);  y[4] = csub(E0, O0);
    y[1] = cadd(E1, wO1); y[5] = csub(E1, wO1);
    y[2] = cadd(E2, wO2); y[6] = csub(E2, wO2);
    y[3] = cadd(E3, wO3); y[7] = csub(E3, wO3);
}

__device__ __forceinline__ void twiddle8(float base, float2* w) {
    float s1, c1, s4, c4;
    __sincosf(base, &s1, &c1);
    __sincosf(4.0f * base, &s4, &c4);
    w[0] = make_float2(1.0f, 0.0f);
    w[1] = make_float2(c1, s1);
    w[2] = cmul(w[1], w[1]);
    w[3] = cmul(w[2], w[1]);
    w[4] = make_float2(c4, s4);
    w[5] = cmul(w[4], w[1]);
    w[6] = cmul(w[4], w[2]);
    w[7] = cmul(w[4], w[3]);
}

// Radix-8 Stockham, N=512 (verified R3): 2 LDS round trips, wave-local.
__device__ __forceinline__ void fft512_stage0_store(float2* rb, int lane, const float2* a) {
    float2 y[8]; dft8(a, y);
    float2 w[8]; twiddle8(-PI_F * (float)lane * (1.0f / 256.0f), w);
#pragma unroll
    for (int r = 0; r < 8; ++r) rb[SW(8 * lane + r)] = cmul(y[r], w[r]);
}

__device__ __forceinline__ void fft512_stage1(float2* rb, int lane) {
    float2 a[8];
#pragma unroll
    for (int u = 0; u < 8; ++u) a[u] = rb[SW(lane + 64 * u)];
    float2 y[8]; dft8(a, y);
    float2 w[8]; twiddle8(-PI_F * (float)(lane >> 3) * (1.0f / 32.0f), w);
    const int qb = (lane & 7) + ((lane >> 3) << 6);
#pragma unroll
    for (int r = 0; r < 8; ++r) rb[SW(qb + 8 * r)] = cmul(y[r], w[r]);
}

__device__ __forceinline__ void fft512_stage2(const float2* rb, int lane, float2* y) {
    float2 a[8];
#pragma unroll
    for (int u = 0; u < 8; ++u) a[u] = rb[SW(lane + 64 * u)];
    dft8(a, y);   // twiddle-free; y[r] = X[lane + 64r] (natural order)
}

// ---------------------------------------------------------------------------
// Row pass: unchanged (2.8 TB/s effective).
// ---------------------------------------------------------------------------
__global__ __launch_bounds__(512, 4)
void row_fft_kernel(const float2* __restrict__ z, const float2* __restrict__ t,
                    float2* __restrict__ fieldsT, int b0) {
    __shared__ float2 buf[8 * 512];   // 32 KiB: FFT regions, then transpose tile
    const int tid  = threadIdx.x;
    const int lane = tid & 63;
    const int g    = tid >> 6;
    const int bid  = blockIdx.x;
    const int hg   = bid & 63;
    const int lb   = bid >> 6;
    const int b    = b0 + lb;
    const int h    = (hg << 3) | g;
    const size_t rowOff = ((size_t)(b * HH + h)) * WW;

    const float2* tr = t + rowOff;
    const float2* zr = z + rowOff;
    float2 tv[8], zv[8];
#pragma unroll
    for (int u = 0; u < 8; ++u) tv[u] = tr[lane + 64 * u];
#pragma unroll
    for (int u = 0; u < 8; ++u) zv[u] = zr[lane + 64 * u];

    float2* rb = buf + (g << 9);
#pragma unroll
    for (int f = 0; f < 2; ++f) {
        float2 a[8];
        if (f == 0) {
#pragma unroll
            for (int u = 0; u < 8; ++u) a[u] = tv[u];
        } else {
#pragma unroll
            for (int u = 0; u < 8; ++u) a[u] = make_float2(zv[u].x - tv[u].x,
                                                           zv[u].y - tv[u].y);
        }
        fft512_stage0_store(rb, lane, a);
        __builtin_amdgcn_wave_barrier();
        fft512_stage1(rb, lane);
        __builtin_amdgcn_wave_barrier();
        float2 y[8];
        fft512_stage2(rb, lane, y);

        __syncthreads();   // all waves done reading their FFT regions
#pragma unroll
        for (int r = 0; r < 8; ++r) {
            int c = lane + (r << 6);
            buf[TSW(c, g)] = y[r];
        }
        __syncthreads();
        float2* outF = fieldsT + ((size_t)(lb * 2 + f) << 18);  // * 512*512
#pragma unroll
        for (int k = 0; k < 8; ++k) {
            int e  = tid + (k << 9);
            int c  = e >> 3;
            int hh = e & 7;
            outF[((size_t)c << 9) + (hg << 3) + hh] = buf[TSW(c, hh)];
        }
        __syncthreads();   // tile region free before next field's stage 0
    }
}

// ---------------------------------------------------------------------------
// Column pass. R2 change: the per-pixel LDS atomic scatter is replaced by a
// DPP-based segmented reduction. Within one binning step r, the 64 lanes hold
// monotone bin indices (dk is single-signed across the instr), so equal bins
// form contiguous lane runs. A VALU-only segmented inclusive scan (DPP
// row_shr within 16-lane rows) collapses each run; only the last lane of a
// run issues ds_atomic_add. Max same-address multiplicity drops 64 -> 4 and
// the DS pipe sees ~#distinct-bins RMWs instead of 64 per instr. Overflow
// pixels map to bin 511 (never read) -> no divergent branch.
// ---------------------------------------------------------------------------
__global__ __launch_bounds__(512, 4)
void col_fft_bin_kernel(const float2* __restrict__ fieldsT,
                        float* __restrict__ partials, int b0) {
    __shared__ float2 buf[8 * 512];   // 32 KiB FFT exchange regions (reused as hists)
    const int tid  = threadIdx.x;
    const int lane = tid & 63;
    const int g    = tid >> 6;
    const int bid  = blockIdx.x;
    const int cg   = bid & 63;
    const int fl   = bid >> 6;
    const int f    = fl & 1;
    const int b    = b0 + (fl >> 1);
    const int c    = (cg << 3) | g;

    const float2* colT = fieldsT + (((size_t)fl << 9) + c) * 512;
    float2 a[8];
#pragma unroll
    for (int u = 0; u < 8; ++u) a[u] = colT[lane + (u << 6)];

    float2* rb = buf + (g << 9);
    fft512_stage0_store(rb, lane, a);
    __builtin_amdgcn_wave_barrier();
    fft512_stage1(rb, lane);
    __builtin_amdgcn_wave_barrier();
    float2 y[8];
    fft512_stage2(rb, lane, y);
    __builtin_amdgcn_wave_barrier();
    __asm__ volatile("" ::: "memory");   // stage2 reads complete before hist zeroing

    // Zero the wave's private 512-float hist (first 256 float2 of its region).
#pragma unroll
    for (int j = 0; j < 4; ++j) rb[lane + (j << 6)] = make_float2(0.0f, 0.0f);
    __builtin_amdgcn_wave_barrier();
    __asm__ volatile("" ::: "memory");

    float* histw = (float*)rb;           // 512 wave-private bins
    const int dc = c - 256;
    const unsigned fc2i = (unsigned)(dc * dc);
    const int l15 = lane & 15;
#pragma unroll
    for (int r = 0; r < 8; ++r) {
        int k  = lane + (r << 6);
        int dk = k - 256;
        unsigned m = (unsigned)(dk * dk) + fc2i;   // 65536 * ellipse, exact, <= 131072
        // bin = #{ j in [1,511] : j^2 * 65536 <= 261121 * m }  (exact integer check)
        int bin = (int)(sqrtf((float)m) * (511.0f / 256.0f));
        unsigned long long rhs = 261121ull * (unsigned long long)m;  // 511^2 * m
        unsigned bp1 = (unsigned)(bin + 1);
        if (((unsigned long long)(bp1 * bp1) << 16) <= rhs) ++bin;
        else if (((unsigned long long)((unsigned)bin * (unsigned)bin) << 16) > rhs) --bin;
        bin = (m < 65536u) ? bin : 511;            // overflow shell -> bin 511 (dead)

        float v = y[r].x * y[r].x + y[r].y * y[r].y;

        // Segmented inclusive scan over equal-bin runs (bins monotone in lane),
        // VALU-only via DPP row_shr within each 16-lane row.
        int nb; float nv;
        nb = DPP_SHR(bin, 1);
        nv = __int_as_float(DPP_SHR(__float_as_int(v), 1));
        v += (l15 >= 1 && nb == bin) ? nv : 0.0f;
        nb = DPP_SHR(bin, 2);
        nv = __int_as_float(DPP_SHR(__float_as_int(v), 2));
        v += (l15 >= 2 && nb == bin) ? nv : 0.0f;
        nb = DPP_SHR(bin, 4);
        nv = __int_as_float(DPP_SHR(__float_as_int(v), 4));
        v += (l15 >= 4 && nb == bin) ? nv : 0.0f;
        nb = DPP_SHR(bin, 8);
        nv = __int_as_float(DPP_SHR(__float_as_int(v), 8));
        v += (l15 >= 8 && nb == bin) ? nv : 0.0f;

        int nxt = DPP_SHL1(bin);                   // bin of lane+1 within the row
        if (l15 == 15 || nxt != bin)               // last lane of its run
            atomicAdd(&histw[bin], v);
    }
    __syncthreads();                     // all wave-private hists final

    // Cross-wave sum (fixed order) + coalesced non-atomic flush.
    float s = 0.0f;
    const float* bufF = (const float*)buf;
#pragma unroll
    for (int gg = 0; gg < 8; ++gg) s += bufF[(gg << 10) + tid];
    partials[(((size_t)cg << 5) + (size_t)(f * NBATCH + b)) * NBINS + tid] = s;
}

// ---------------------------------------------------------------------------
// Sum the 64 column-group partials: bins[fl][bin] = sum_cg partials[cg][fl][bin].
// ---------------------------------------------------------------------------
__global__ __launch_bounds__(512)
void reduce_bins_kernel(const float* __restrict__ partials, float* __restrict__ bins) {
    __shared__ float red[512];
    const int tid = threadIdx.x;
    const int fl  = blockIdx.x >> 2;          // 0..31  (f*16+b)
    const int q   = blockIdx.x & 3;           // quarter of the 512 bins
    const int bin = (q << 7) + (tid & 127);
    const int ch  = tid >> 7;                 // 0..3 -> 16 cg each
    float s = 0.0f;
#pragma unroll
    for (int j = 0; j < 16; ++j) {
        int cg = (ch << 4) + j;
        s += partials[((size_t)(cg << 5) + fl) * NBINS + bin];
    }
    red[tid] = s;
    __syncthreads();
    if (tid < 128) {
        bins[(size_t)fl * NBINS + bin] =
            red[tid] + red[tid + 128] + red[tid + 256] + red[tid + 384];
    }
}

// ---------------------------------------------------------------------------
// Loss: single block reads the 64 KiB bins array.
// ---------------------------------------------------------------------------
__global__ __launch_bounds__(512)
void loss_kernel(const float* __restrict__ bins, float* __restrict__ outp) {
    __shared__ float red[512];
    const int tid = threadIdx.x;
    float acc = 0.0f;
    if (tid < 511) {
#pragma unroll 4
        for (int b = 0; b < NBATCH; ++b) {
            float ns = bins[((size_t)b) * NBINS + tid];
            float es = bins[((size_t)(NBATCH + b)) * NBINS + tid];
            acc += es / fmaxf(ns, 1e-8f);
        }
    }
    red[tid] = acc;
    __syncthreads();
    for (int s = 256; s > 0; s >>= 1) {
        if (tid < s) red[tid] += red[tid + s];
        __syncthreads();
    }
    if (tid == 0) outp[0] = red[0] * (1.0f / NBATCH);
}

// ---------------------------------------------------------------------------
extern "C" void kernel_launch(void* const* d_in, const int* in_sizes, int n_in,
                              void* d_out, int out_size, void* d_ws, size_t ws_size,
                              hipStream_t stream) {
    const float2* z = (const float2*)d_in[0];
    const float2* t = (const float2*)d_in[1];
    float* outp = (float*)d_out;

    const size_t partialsBytes = 64ull * 2 * NBATCH * NBINS * sizeof(float);  // 4 MiB
    const size_t binsBytes     = (size_t)2 * NBATCH * NBINS * sizeof(float);  // 64 KiB
    const size_t fixedBytes    = partialsBytes + binsBytes;
    const size_t fpb = (size_t)2 * HH * WW * sizeof(float2);                  // 4 MiB/batch

    int CB = 16;
    while (CB > 1 && fixedBytes + (size_t)CB * fpb > ws_size) CB >>= 1;

    float*  partials = (float*)d_ws;
    float*  bins     = (float*)((char*)d_ws + partialsBytes);
    float2* fieldsT  = (float2*)((char*)d_ws + fixedBytes);

    for (int b0 = 0; b0 < NBATCH; b0 += CB) {
        row_fft_kernel<<<CB * 64, 512, 0, stream>>>(z, t, fieldsT, b0);
        col_fft_bin_kernel<<<CB * 2 * 64, 512, 0, stream>>>(fieldsT, partials, b0);
    }
    reduce_bins_kernel<<<128, 512, 0, stream>>>(partials, bins);
    loss_kernel<<<1, 512, 0, stream>>>(bins, outp);
}